// Round 3
// baseline (5095.313 us; speedup 1.0000x reference)
//
#include <hip/hip_runtime.h>
#include <stdint.h>

#define NVOX 128
#define VOL  (NVOX * NVOX * NVOX)
#define LO   (-200.0f)
#define VPIX 3.125f            // 400/128
#define INV_V 0.32f            // 1/3.125 exact
// kw^2 = 9/pi ; -0.5/kw^2 = -pi/18
#define NEG_HALF_INV_KW2 (-0.17453292519943295f)
#define NXCD 8

// XCD-local (L2-scope) f32 atomic add: no sc0/sc1 bits -> RMW executes in the
// local TCC instead of crossing the fabric to the memory-side atomic units.
// ONLY safe when all updaters of the address run on the same XCD.
__device__ __forceinline__ void atomic_add_l2(float* p, float v) {
    asm volatile("global_atomic_add_f32 %0, %1, off" :: "v"(p), "v"(v) : "memory");
}

__device__ __forceinline__ int xcc_id() {
    // s_getreg hwreg(HW_REG_XCC_ID=20, offset=0, size=4)  [learn_hip m09]
    return (int)(__builtin_amdgcn_s_getreg(20 | (3 << 11)) & (NXCD - 1));
}

// Deposit into vol[iy][iz][k] (k = lane dim innermost -> coalesced atomics).
// LOCAL=1: vol_base = 8 per-XCD replicas, L2-scope atomics.
// LOCAL=0: vol_base = single volume, device-scope atomics.
template<bool LOCAL>
__global__ __launch_bounds__(256) void bp_nat(
    const float* __restrict__ lors,   // (6, nlor) row-major
    const float* __restrict__ proj,
    float* __restrict__ vol_base,
    int nlor)
{
    float* vol = vol_base;
    if (LOCAL) vol += (size_t)xcc_id() * VOL;

    int tid = blockIdx.x * 256 + threadIdx.x;
    int k = tid & (NVOX - 1);
    int n = tid >> 7;
    if (n >= nlor) return;

    float p1x = lors[0 * nlor + n];
    float p1y = lors[1 * nlor + n];
    float p1z = lors[2 * nlor + n];
    float p2x = lors[3 * nlor + n];
    float p2y = lors[4 * nlor + n];
    float p2z = lors[5 * nlor + n];
    float pr  = proj[n];

    float xk = LO + (k + 0.5f) * VPIX;
    float t  = (xk - p1x) / (p2x - p1x);
    if (t < 0.0f || t > 1.0f) return;

    float y = p1y + t * (p2y - p1y);
    float z = p1z + t * (p2z - p1z);

    float fy = (y - LO) * INV_V - 0.5f;
    float fz = (z - LO) * INV_V - 0.5f;
    int iy0 = (int)floorf(fy) - 1;
    int iz0 = (int)floorf(fz) - 1;

    float wy[3], wz[3];
    #pragma unroll
    for (int o = 0; o < 3; ++o) {
        int iy = iy0 + o;
        float cy = LO + (iy + 0.5f) * VPIX;
        float dy = cy - y;
        wy[o] = (iy >= 0 && iy < NVOX) ? __expf(NEG_HALF_INV_KW2 * dy * dy) * pr : 0.0f;

        int iz = iz0 + o;
        float cz = LO + (iz + 0.5f) * VPIX;
        float dz = cz - z;
        wz[o] = (iz >= 0 && iz < NVOX) ? __expf(NEG_HALF_INV_KW2 * dz * dz) : 0.0f;
    }

    #pragma unroll
    for (int oy = 0; oy < 3; ++oy) {
        if (wy[oy] == 0.0f) continue;
        int iy = iy0 + oy;
        #pragma unroll
        for (int oz = 0; oz < 3; ++oz) {
            if (wz[oz] == 0.0f) continue;
            int iz = iz0 + oz;
            float w = wy[oy] * wz[oz];
            float* p = &vol[(iy * NVOX + iz) * NVOX + k];
            if (LOCAL) atomic_add_l2(p, w);
            else       atomicAdd(p, w);
        }
    }
}

// Ultra-fallback: direct scatter to out for y/z directions (round-1 style).
template<int DIR>
__global__ __launch_bounds__(256) void bp_direct(
    const float* __restrict__ lors, const float* __restrict__ proj,
    float* __restrict__ out, int nlor)
{
    int tid = blockIdx.x * 256 + threadIdx.x;
    int k = tid & (NVOX - 1);
    int n = tid >> 7;
    if (n >= nlor) return;

    float p1x = lors[0 * nlor + n];
    float p1y = lors[1 * nlor + n];
    float p1z = lors[2 * nlor + n];
    float p2x = lors[3 * nlor + n];
    float p2y = lors[4 * nlor + n];
    float p2z = lors[5 * nlor + n];
    float pr  = proj[n];

    float xk = LO + (k + 0.5f) * VPIX;
    float t  = (xk - p1x) / (p2x - p1x);
    if (t < 0.0f || t > 1.0f) return;

    float y = p1y + t * (p2y - p1y);
    float z = p1z + t * (p2z - p1z);
    float fy = (y - LO) * INV_V - 0.5f;
    float fz = (z - LO) * INV_V - 0.5f;
    int iy0 = (int)floorf(fy) - 1;
    int iz0 = (int)floorf(fz) - 1;

    float wy[3], wz[3];
    #pragma unroll
    for (int o = 0; o < 3; ++o) {
        int iy = iy0 + o;
        float cy = LO + (iy + 0.5f) * VPIX;
        float dy = cy - y;
        wy[o] = (iy >= 0 && iy < NVOX) ? __expf(NEG_HALF_INV_KW2 * dy * dy) * pr : 0.0f;
        int iz = iz0 + o;
        float cz = LO + (iz + 0.5f) * VPIX;
        float dz = cz - z;
        wz[o] = (iz >= 0 && iz < NVOX) ? __expf(NEG_HALF_INV_KW2 * dz * dz) : 0.0f;
    }
    #pragma unroll
    for (int oy = 0; oy < 3; ++oy) {
        if (wy[oy] == 0.0f) continue;
        int iy = iy0 + oy;
        #pragma unroll
        for (int oz = 0; oz < 3; ++oz) {
            if (wz[oz] == 0.0f) continue;
            int iz = iz0 + oz;
            int idx = (DIR == 1) ? (iy * NVOX + k) * NVOX + iz
                                 : (k * NVOX + iy) * NVOX + iz;
            atomicAdd(&out[idx], wy[oy] * wz[oz]);
        }
    }
}

// out[idx] += sum_r reps[r][idx]   (x-direction: natural layout == out layout)
template<int NREP>
__global__ __launch_bounds__(256) void merge_x(
    float* __restrict__ out, const float* __restrict__ reps)
{
    int idx = blockIdx.x * 256 + threadIdx.x;
    float s = 0.0f;
    #pragma unroll
    for (int r = 0; r < NREP; ++r) s += reps[(size_t)r * VOL + idx];
    out[idx] += s;
}

// Transposing merge via LDS 64x64 subtiles (both global sides coalesced).
// MODE 0 (y-dir): out[fixed][row][c] += sum_r reps[r][fixed][c][row]
// MODE 1 (z-dir): out[row][fixed][c] += sum_r reps[r][fixed][c][row]
template<int MODE, int NREP>
__global__ __launch_bounds__(256) void merge_t(
    float* __restrict__ out, const float* __restrict__ reps)
{
    __shared__ float T[64][65];
    int fixed = blockIdx.x;
    int lane = threadIdx.x & 63;
    int quad = threadIdx.x >> 6;   // 0..3

    for (int ch = 0; ch < 2; ++ch) {       // half of c (input middle index)
        for (int rh = 0; rh < 2; ++rh) {   // half of row (input inner index)
            for (int cp = quad; cp < 64; cp += 4) {
                size_t base = ((size_t)fixed * NVOX + (ch * 64 + cp)) * NVOX
                              + (rh * 64 + lane);
                float s = 0.0f;
                #pragma unroll
                for (int r = 0; r < NREP; ++r) s += reps[(size_t)r * VOL + base];
                T[cp][lane] = s;           // stride-1 write: conflict-free
            }
            __syncthreads();
            for (int rp = quad; rp < 64; rp += 4) {
                int row = rh * 64 + rp;
                int c   = ch * 64 + lane;
                float v = T[lane][rp];     // stride-65 read: conflict-free
                size_t oidx = (MODE == 0)
                    ? ((size_t)fixed * NVOX + row) * NVOX + c
                    : ((size_t)row * NVOX + fixed) * NVOX + c;
                out[oidx] += v;            // blocks own disjoint out slices
            }
            __syncthreads();
        }
    }
}

extern "C" void kernel_launch(void* const* d_in, const int* in_sizes, int n_in,
                              void* d_out, int out_size, void* d_ws, size_t ws_size,
                              hipStream_t stream) {
    const float* xlors = (const float*)d_in[4];
    const float* ylors = (const float*)d_in[5];
    const float* zlors = (const float*)d_in[6];
    const float* xproj = (const float*)d_in[7];
    const float* yproj = (const float*)d_in[8];
    const float* zproj = (const float*)d_in[9];
    float* out = (float*)d_out;
    const int nlor = in_sizes[7];

    const int total  = nlor * NVOX;
    const int blocks = (total + 255) / 256;
    const size_t volB = (size_t)VOL * sizeof(float);

    hipMemsetAsync(d_out, 0, volB, stream);

    if (ws_size >= (size_t)NXCD * volB) {
        // ---- per-XCD replica path: atomics stay in XCD-local L2 ----
        float* reps = (float*)d_ws;

        hipMemsetAsync(reps, 0, NXCD * volB, stream);
        bp_nat<true><<<blocks, 256, 0, stream>>>(xlors, xproj, reps, nlor);
        merge_x<NXCD><<<VOL / 256, 256, 0, stream>>>(out, reps);

        hipMemsetAsync(reps, 0, NXCD * volB, stream);
        bp_nat<true><<<blocks, 256, 0, stream>>>(ylors, yproj, reps, nlor);
        merge_t<0, NXCD><<<NVOX, 256, 0, stream>>>(out, reps);

        hipMemsetAsync(reps, 0, NXCD * volB, stream);
        bp_nat<true><<<blocks, 256, 0, stream>>>(zlors, zproj, reps, nlor);
        merge_t<1, NXCD><<<NVOX, 256, 0, stream>>>(out, reps);
    } else if (ws_size >= 2 * volB) {
        // ---- round-2 path: direction-natural layouts, device-scope atomics ----
        float* Sy = (float*)d_ws;
        float* Sz = Sy + VOL;
        hipMemsetAsync(d_ws, 0, 2 * volB, stream);

        bp_nat<false><<<blocks, 256, 0, stream>>>(xlors, xproj, out, nlor);
        bp_nat<false><<<blocks, 256, 0, stream>>>(ylors, yproj, Sy, nlor);
        bp_nat<false><<<blocks, 256, 0, stream>>>(zlors, zproj, Sz, nlor);
        merge_t<0, 1><<<NVOX, 256, 0, stream>>>(out, Sy);
        merge_t<1, 1><<<NVOX, 256, 0, stream>>>(out, Sz);
    } else {
        // ---- ultra-fallback: direct scatter ----
        bp_nat<false><<<blocks, 256, 0, stream>>>(xlors, xproj, out, nlor);
        bp_direct<1><<<blocks, 256, 0, stream>>>(ylors, yproj, out, nlor);
        bp_direct<2><<<blocks, 256, 0, stream>>>(zlors, zproj, out, nlor);
    }
}